// Round 9
// baseline (306.172 us; speedup 1.0000x reference)
//
#include <hip/hip_runtime.h>
#include <hip/hip_bf16.h>
#include <math.h>

typedef __bf16 bf16;
typedef bf16 bf16x4 __attribute__((ext_vector_type(4)));
typedef bf16 bf16x8 __attribute__((ext_vector_type(8)));
typedef float floatx4 __attribute__((ext_vector_type(4)));

#define MFMA16(a, b, c) __builtin_amdgcn_mfma_f32_16x16x32_bf16(a, b, c, 0, 0, 0)

__device__ __forceinline__ void split2(float v, bf16& h, bf16& l) {
    h = (bf16)v;
    l = (bf16)(v - (float)h);
}

// async global->LDS, 16 B per lane; LDS dest = wave-uniform base + lane*16
__device__ __forceinline__ void gload16(const bf16* g, bf16* l) {
    __builtin_amdgcn_global_load_lds(
        (const __attribute__((address_space(1))) void*)g,
        (__attribute__((address_space(3))) void*)l, 16, 0, 0);
}

// ---------------------------------------------------------------------------
// K0: z<4: transpose+split fp32 weights W[k][n] -> hi/lo bf16 Wt[n][k]
//     z==4: split x fp32 -> hi/lo bf16 (flat)
// ---------------------------------------------------------------------------
__global__ void prep_kernel(const float* __restrict__ xf,
                            const float* __restrict__ wq, const float* __restrict__ wk,
                            const float* __restrict__ wv, const float* __restrict__ wo,
                            bf16* __restrict__ xh, bf16* __restrict__ xl,
                            bf16* __restrict__ wt_qkv_h, bf16* __restrict__ wt_qkv_l,
                            bf16* __restrict__ wt_o_h) {
    const int z = blockIdx.z;
    if (z == 4) {
        const int tid = threadIdx.y * 32 + threadIdx.x;
        const int bid = blockIdx.y * 32 + blockIdx.x;
        const size_t i = ((size_t)bid * 256 + tid) * 16;
#pragma unroll
        for (int half = 0; half < 2; half++) {
            float4 a = *(const float4*)(xf + i + half * 8);
            float4 b = *(const float4*)(xf + i + half * 8 + 4);
            bf16x8 oh, ol;
            float f[8] = {a.x, a.y, a.z, a.w, b.x, b.y, b.z, b.w};
#pragma unroll
            for (int j = 0; j < 8; j++) { bf16 h, l; split2(f[j], h, l); oh[j] = h; ol[j] = l; }
            *(bf16x8*)(xh + i + half * 8) = oh;
            *(bf16x8*)(xl + i + half * 8) = ol;
        }
        return;
    }
    const float* src = (z == 0) ? wq : (z == 1) ? wk : (z == 2) ? wv : wo;
    bf16* dsth = (z < 3) ? (wt_qkv_h + (size_t)z * 1024 * 1024) : wt_o_h;
    bf16* dstl = (z < 3) ? (wt_qkv_l + (size_t)z * 1024 * 1024) : nullptr;
    __shared__ float tile[32][33];
    const int x0 = blockIdx.x * 32, y0 = blockIdx.y * 32;
    const int tx = threadIdx.x, ty = threadIdx.y;  // (32,8)
    for (int i = 0; i < 32; i += 8)
        tile[ty + i][tx] = src[(size_t)(y0 + ty + i) * 1024 + x0 + tx];
    __syncthreads();
    for (int i = 0; i < 32; i += 8) {
        bf16 h, l;
        split2(tile[tx][ty + i], h, l);
        dsth[(size_t)(x0 + ty + i) * 1024 + y0 + tx] = h;
        if (dstl) dstl[(size_t)(x0 + ty + i) * 1024 + y0 + tx] = l;
    }
}

// ---------------------------------------------------------------------------
// K1: fused QKV GEMM, split-bf16, m97 staging, MFMA16 inner loop,
// XCD-AWARE SWIZZLE: xcd = lin&7 owns n-tiles {xcd, xcd+8, xcd+16} (one per
// Q/K/V slab, load-balanced) for all 32 m-tiles -> B tiles stay L2-resident.
// ---------------------------------------------------------------------------
__global__ __launch_bounds__(256, 2) void gemm_qkv3(
    const bf16* __restrict__ Ah, const bf16* __restrict__ Al,
    const bf16* __restrict__ Bth, const bf16* __restrict__ Btl,
    const float* __restrict__ bq, const float* __restrict__ bk,
    const float* __restrict__ bv,
    bf16* __restrict__ Qh, bf16* __restrict__ Ql,
    bf16* __restrict__ Kh, bf16* __restrict__ Kl, bf16* __restrict__ VtG) {
    __shared__ bf16 Ash[128 * 32];
    __shared__ bf16 Asl[128 * 32];
    __shared__ bf16 Bsh[128 * 32];
    __shared__ bf16 Bsl[128 * 32];

    const int t = threadIdx.x;
    const int lane = t & 63, wave = t >> 6;
    const int quad = lane >> 4, l16 = lane & 15;
    // XCD-aware swizzle (8 XCDs, round-robin dispatch: xcd = lin % 8)
    const int lin = blockIdx.y * 32 + blockIdx.x;
    const int xcd = lin & 7, slot = lin >> 3;        // slot in [0,96)
    const int m0 = (slot / 3) * 128;                 // 32 m-tiles
    const int n0 = ((slot % 3) * 8 + xcd) * 128;     // one n-tile per slab
    const int wm = (wave >> 1) * 64, wn = (wave & 1) * 64;
    const bool full = (n0 < 2048);

    const int srow = wave * 16 + (lane >> 2);
    const int scol = (lane & 3) * 8;
    const bf16* gAh = Ah + (size_t)(m0 + srow) * 1024 + scol;
    const bf16* gAl = Al + (size_t)(m0 + srow) * 1024 + scol;
    const bf16* gBh = Bth + (size_t)(n0 + srow) * 1024 + scol;
    const bf16* gBl = Btl + (size_t)(n0 + srow) * 1024 + scol;
    bf16* lAh = &Ash[wave * 16 * 32];
    bf16* lAl = &Asl[wave * 16 * 32];
    bf16* lBh = &Bsh[wave * 16 * 32];
    bf16* lBl = &Bsl[wave * 16 * 32];

    floatx4 acc[4][4] = {};

    for (int k0 = 0; k0 < 1024; k0 += 32) {
        gload16(gAh + k0, lAh);
        gload16(gAh + 64 * 1024 + k0, lAh + 64 * 32);
        gload16(gBh + k0, lBh);
        gload16(gBh + 64 * 1024 + k0, lBh + 64 * 32);
        if (full) {
            gload16(gAl + k0, lAl);
            gload16(gAl + 64 * 1024 + k0, lAl + 64 * 32);
            gload16(gBl + k0, lBl);
            gload16(gBl + 64 * 1024 + k0, lBl + 64 * 32);
        }
        __syncthreads();
        bf16x8 afh[4], bfh[4];
#pragma unroll
        for (int i = 0; i < 4; i++)
            afh[i] = *(bf16x8*)&Ash[(wm + i * 16 + l16) * 32 + quad * 8];
#pragma unroll
        for (int j = 0; j < 4; j++)
            bfh[j] = *(bf16x8*)&Bsh[(wn + j * 16 + l16) * 32 + quad * 8];
        if (full) {
            bf16x8 afl[4], bfl[4];
#pragma unroll
            for (int i = 0; i < 4; i++)
                afl[i] = *(bf16x8*)&Asl[(wm + i * 16 + l16) * 32 + quad * 8];
#pragma unroll
            for (int j = 0; j < 4; j++)
                bfl[j] = *(bf16x8*)&Bsl[(wn + j * 16 + l16) * 32 + quad * 8];
#pragma unroll
            for (int i = 0; i < 4; i++)
#pragma unroll
                for (int j = 0; j < 4; j++) {
                    acc[i][j] = MFMA16(afh[i], bfh[j], acc[i][j]);
                    acc[i][j] = MFMA16(afh[i], bfl[j], acc[i][j]);
                    acc[i][j] = MFMA16(afl[i], bfh[j], acc[i][j]);
                }
        } else {
#pragma unroll
            for (int i = 0; i < 4; i++)
#pragma unroll
                for (int j = 0; j < 4; j++)
                    acc[i][j] = MFMA16(afh[i], bfh[j], acc[i][j]);
        }
        __syncthreads();
    }

    const int which = n0 >> 10;  // 0=Q 1=K 2=V
    const float* bias = (which == 0) ? bq : (which == 1) ? bk : bv;
#pragma unroll
    for (int i = 0; i < 4; i++)
#pragma unroll
        for (int j = 0; j < 4; j++) {
            const int col = n0 + wn + j * 16 + l16;
            const int o = col & 1023;
            const int h = o >> 6, d = o & 63;
            const float bvv = bias[o];
            const int gm0 = m0 + wm + i * 16 + quad * 4;
            const int b = gm0 >> 11;
            if (which == 2) {
                bf16x4 pv;
#pragma unroll
                for (int r = 0; r < 4; r++) pv[r] = (bf16)(acc[i][j][r] + bvv);
                const int s0 = gm0 & 2047;
                *(bf16x4*)&VtG[((size_t)((b * 16 + h) * 64 + d)) * 2048 + s0] = pv;
            } else {
#pragma unroll
                for (int r = 0; r < 4; r++) {
                    const int gm = gm0 + r;
                    const int s = gm & 2047;
                    const size_t idx = (size_t)((b * 16 + h) * 2048 + s) * 64 + d;
                    const float val = acc[i][j][r] + bvv;
                    bf16 hi, lo;
                    split2(val, hi, lo);
                    if (which == 0) { Qh[idx] = hi; Ql[idx] = lo; }
                    else            { Kh[idx] = hi; Kl[idx] = lo; }
                }
            }
        }
}

// ---------------------------------------------------------------------------
// K1b: precompute ||k||^2 per key row (fp32 from hi+lo), knG[bh*2048+s]
// ---------------------------------------------------------------------------
__global__ void kn_kernel(const bf16* __restrict__ Kh, const bf16* __restrict__ Kl,
                          float* __restrict__ knG) {
    const int i = blockIdx.x * 256 + threadIdx.x;
    const bf16* ph = Kh + (size_t)i * 64;
    const bf16* pl = Kl + (size_t)i * 64;
    float s = 0.f;
#pragma unroll
    for (int d0 = 0; d0 < 64; d0 += 8) {
        bf16x8 vh = *(const bf16x8*)(ph + d0);
        bf16x8 vl = *(const bf16x8*)(pl + d0);
#pragma unroll
        for (int j = 0; j < 8; j++) { float x = (float)vh[j] + (float)vl[j]; s += x * x; }
    }
    knG[i] = s;
}

// ---------------------------------------------------------------------------
// K2: flash attention, YAT scores, transposed orientation, 32 q per wave,
//   double-buffered K/V/kn staging (one barrier per 64-key chunk).
// ---------------------------------------------------------------------------
__global__ __launch_bounds__(256, 2) void attn_kernel(
    const bf16* __restrict__ Qh, const bf16* __restrict__ Ql,
    const bf16* __restrict__ Kh, const bf16* __restrict__ Kl,
    const bf16* __restrict__ VtG, const float* __restrict__ knG,
    bf16* __restrict__ O, const float* __restrict__ alphap) {
    __shared__ bf16 Ksh[2][64 * 72];
    __shared__ bf16 Ksl[2][64 * 72];
    __shared__ bf16 Vs[2][64 * 72];
    __shared__ bf16 Pt[4][32 * 72];
    __shared__ float knL[2][64];

    const int t = threadIdx.x, lane = t & 63, wave = t >> 6;
    const int quad = lane >> 4, l16 = lane & 15;
    const int bh = blockIdx.x;
    const int qw = blockIdx.y * 128 + wave * 32;

    const float alpha = alphap[0];
    const float C = powf(8.0f / log1pf(64.0f), alpha) * 1.44269504f;

    const size_t qrow0 = ((size_t)bh * 2048 + qw + l16) * 64;
    const size_t qrow1 = qrow0 + 16 * 64;
    bf16x8 bq0h[2], bq1h[2], bq0l[2], bq1l[2];
    bq0h[0] = *(const bf16x8*)(Qh + qrow0 + quad * 8);
    bq1h[0] = *(const bf16x8*)(Qh + qrow0 + 32 + quad * 8);
    bq0l[0] = *(const bf16x8*)(Ql + qrow0 + quad * 8);
    bq1l[0] = *(const bf16x8*)(Ql + qrow0 + 32 + quad * 8);
    bq0h[1] = *(const bf16x8*)(Qh + qrow1 + quad * 8);
    bq1h[1] = *(const bf16x8*)(Qh + qrow1 + 32 + quad * 8);
    bq0l[1] = *(const bf16x8*)(Ql + qrow1 + quad * 8);
    bq1l[1] = *(const bf16x8*)(Ql + qrow1 + 32 + quad * 8);

    float qne[2];
#pragma unroll
    for (int qg = 0; qg < 2; qg++) {
        float qn = 0.f;
#pragma unroll
        for (int j = 0; j < 8; j++) {
            float x0 = (float)bq0h[qg][j] + (float)bq0l[qg][j];
            float x1 = (float)bq1h[qg][j] + (float)bq1l[qg][j];
            qn += x0 * x0 + x1 * x1;
        }
        qn += __shfl_xor(qn, 16, 64);
        qn += __shfl_xor(qn, 32, 64);
        qne[qg] = qn + 1e-5f;
    }

    floatx4 acco[2][4] = {};
    float m_i[2] = {0.f, 0.f};
    float l_i[2] = {0.f, 0.f};

    const int srow = t >> 3;
    const int scol = (t & 7) * 8;
    const size_t vrow0 = ((size_t)bh * 64 + srow) * 2048;
    const size_t vrow1 = ((size_t)bh * 64 + srow + 32) * 2048;
    const float* knB = knG + (size_t)bh * 2048;

    auto do_chunk = [&](int ib) {
        const bf16* KshC = Ksh[ib];
        const bf16* KslC = Ksl[ib];
        const bf16* VsC = Vs[ib];
        const float* knC = knL[ib];
        float pbuf[2][4][4];
        float mloc[2] = {0.f, 0.f};
#pragma unroll
        for (int sub = 0; sub < 4; sub++) {
            bf16x8 a0h = *(bf16x8*)&KshC[(sub * 16 + l16) * 72 + quad * 8];
            bf16x8 a1h = *(bf16x8*)&KshC[(sub * 16 + l16) * 72 + 32 + quad * 8];
            bf16x8 a0l = *(bf16x8*)&KslC[(sub * 16 + l16) * 72 + quad * 8];
            bf16x8 a1l = *(bf16x8*)&KslC[(sub * 16 + l16) * 72 + 32 + quad * 8];
            floatx4 ac0 = {}, ac1 = {};
            ac0 = MFMA16(a0h, bq0h[0], ac0);
            ac0 = MFMA16(a1h, bq1h[0], ac0);
            ac0 = MFMA16(a0h, bq0l[0], ac0);
            ac0 = MFMA16(a1h, bq1l[0], ac0);
            ac0 = MFMA16(a0l, bq0h[0], ac0);
            ac0 = MFMA16(a1l, bq1h[0], ac0);
            ac1 = MFMA16(a0h, bq0h[1], ac1);
            ac1 = MFMA16(a1h, bq1h[1], ac1);
            ac1 = MFMA16(a0h, bq0l[1], ac1);
            ac1 = MFMA16(a1h, bq1l[1], ac1);
            ac1 = MFMA16(a0l, bq0h[1], ac1);
            ac1 = MFMA16(a1l, bq1h[1], ac1);
            const floatx4 knv = *(const floatx4*)&knC[sub * 16 + quad * 4];
#pragma unroll
            for (int r = 0; r < 4; r++) {
                const float d0 = ac0[r];
                const float d1 = ac1[r];
                const float e0 = fmaf(-2.0f, d0, qne[0] + knv[r]);
                const float e1 = fmaf(-2.0f, d1, qne[1] + knv[r]);
                const float s0 = C * d0 * d0 * __builtin_amdgcn_rcpf(e0);
                const float s1 = C * d1 * d1 * __builtin_amdgcn_rcpf(e1);
                pbuf[0][sub][r] = s0;
                pbuf[1][sub][r] = s1;
                mloc[0] = fmaxf(mloc[0], s0);
                mloc[1] = fmaxf(mloc[1], s1);
            }
        }
        bf16* Pw = Pt[wave];
#pragma unroll
        for (int qg = 0; qg < 2; qg++) {
            float mx = mloc[qg];
            mx = fmaxf(mx, __shfl_xor(mx, 16, 64));
            mx = fmaxf(mx, __shfl_xor(mx, 32, 64));
            const float mnew = fmaxf(m_i[qg], mx);
            const float al = __builtin_amdgcn_exp2f(m_i[qg] - mnew);
            float rs = 0.f;
            bf16* Pq = Pw + (qg * 16 + l16) * 72;
#pragma unroll
            for (int sub = 0; sub < 4; sub++) {
                bf16x4 pv;
#pragma unroll
                for (int r = 0; r < 4; r++) {
                    const float p = __builtin_amdgcn_exp2f(pbuf[qg][sub][r] - mnew);
                    rs += p;
                    pv[r] = (bf16)p;
                }
                *(bf16x4*)&Pq[sub * 16 + quad * 4] = pv;
            }
            rs += __shfl_xor(rs, 16, 64);
            rs += __shfl_xor(rs, 32, 64);
            l_i[qg] = l_i[qg] * al + rs;
            m_i[qg] = mnew;
#pragma unroll
            for (int dsub = 0; dsub < 4; dsub++) acco[qg][dsub] *= al;
        }
        bf16x8 bp0[2], bp1[2];
#pragma unroll
        for (int qg = 0; qg < 2; qg++) {
            bp0[qg] = *(bf16x8*)&Pw[(qg * 16 + l16) * 72 + quad * 8];
            bp1[qg] = *(bf16x8*)&Pw[(qg * 16 + l16) * 72 + 32 + quad * 8];
        }
#pragma unroll
        for (int dsub = 0; dsub < 4; dsub++) {
            bf16x8 a0 = *(bf16x8*)&VsC[(dsub * 16 + l16) * 72 + quad * 8];
            bf16x8 a1 = *(bf16x8*)&VsC[(dsub * 16 + l16) * 72 + 32 + quad * 8];
            acco[0][dsub] = MFMA16(a0, bp0[0], acco[0][dsub]);
            acco[0][dsub] = MFMA16(a1, bp1[0], acco[0][dsub]);
            acco[1][dsub] = MFMA16(a0, bp0[1], acco[1][dsub]);
            acco[1][dsub] = MFMA16(a1, bp1[1], acco[1][dsub]);
        }
    };

    {
        const size_t kb = (size_t)(bh * 2048) * 64;
        bf16x8 k0 = *(const bf16x8*)(Kh + kb + srow * 64 + scol);
        bf16x8 k1 = *(const bf16x8*)(Kh + kb + (32 + srow) * 64 + scol);
        bf16x8 c0 = *(const bf16x8*)(Kl + kb + srow * 64 + scol);
        bf16x8 c1 = *(const bf16x8*)(Kl + kb + (32 + srow) * 64 + scol);
        bf16x8 v0 = *(const bf16x8*)(VtG + vrow0 + scol);
        bf16x8 v1 = *(const bf16x8*)(VtG + vrow1 + scol);
        *(bf16x8*)&Ksh[0][srow * 72 + scol] = k0;
        *(bf16x8*)&Ksh[0][(32 + srow) * 72 + scol] = k1;
        *(bf16x8*)&Ksl[0][srow * 72 + scol] = c0;
        *(bf16x8*)&Ksl[0][(32 + srow) * 72 + scol] = c1;
        *(bf16x8*)&Vs[0][srow * 72 + scol] = v0;
        *(bf16x8*)&Vs[0][(32 + srow) * 72 + scol] = v1;
        if (t < 16) *(float4*)&knL[0][t * 4] = *(const float4*)(knB + t * 4);
    }
    __syncthreads();

    for (int ic = 0; ic < 31; ic++) {
        const int cur = ic & 1, nxt = cur ^ 1;
        const int kc = (ic + 1) * 64;
        const size_t kb = (size_t)(bh * 2048 + kc) * 64;
        bf16x8 nk0 = *(const bf16x8*)(Kh + kb + srow * 64 + scol);
        bf16x8 nk1 = *(const bf16x8*)(Kh + kb + (32 + srow) * 64 + scol);
        bf16x8 nc0 = *(const bf16x8*)(Kl + kb + srow * 64 + scol);
        bf16x8 nc1 = *(const bf16x8*)(Kl + kb + (32 + srow) * 64 + scol);
        bf16x8 nv0 = *(const bf16x8*)(VtG + vrow0 + kc + scol);
        bf16x8 nv1 = *(const bf16x8*)(VtG + vrow1 + kc + scol);
        float4 nkn;
        if (t < 16) nkn = *(const float4*)(knB + kc + t * 4);

        do_chunk(cur);

        *(bf16x8*)&Ksh[nxt][srow * 72 + scol] = nk0;
        *(bf16x8*)&Ksh[nxt][(32 + srow) * 72 + scol] = nk1;
        *(bf16x8*)&Ksl[nxt][srow * 72 + scol] = nc0;
        *(bf16x8*)&Ksl[nxt][(32 + srow) * 72 + scol] = nc1;
        *(bf16x8*)&Vs[nxt][srow * 72 + scol] = nv0;
        *(bf16x8*)&Vs[nxt][(32 + srow) * 72 + scol] = nv1;
        if (t < 16) *(float4*)&knL[nxt][t * 4] = nkn;
        __syncthreads();
    }
    do_chunk(1);

    const int b = bh >> 4, h = bh & 15;
#pragma unroll
    for (int qg = 0; qg < 2; qg++) {
        const int s = qw + qg * 16 + l16;
        const float rl = 1.0f / l_i[qg];
        const size_t obase = (size_t)(b * 2048 + s) * 1024 + h * 64;
#pragma unroll
        for (int dsub = 0; dsub < 4; dsub++) {
            bf16x4 ov;
#pragma unroll
            for (int r = 0; r < 4; r++) ov[r] = (bf16)(acco[qg][dsub][r] * rl);
            *(bf16x4*)&O[obase + dsub * 16 + quad * 4] = ov;
        }
    }
}

// ---------------------------------------------------------------------------
// K3: out-proj GEMM (single bf16 pass, m97 staging, XCD swizzle), fp32 out
// ---------------------------------------------------------------------------
__global__ __launch_bounds__(256, 2) void gemm_out(
    const bf16* __restrict__ A, const bf16* __restrict__ Bt,
    const float* __restrict__ bias, float* __restrict__ outC) {
    __shared__ bf16 As[128 * 32];
    __shared__ bf16 Bs[128 * 32];

    const int t = threadIdx.x;
    const int lane = t & 63, wave = t >> 6;
    const int quad = lane >> 4, l16 = lane & 15;
    // XCD swizzle: xcd owns n-tile n0 = xcd*128 for all 32 m-tiles
    const int lin = blockIdx.y * 32 + blockIdx.x;
    const int m0 = (lin >> 3) * 128;
    const int n0 = (lin & 7) * 128;
    const int wm = (wave >> 1) * 64, wn = (wave & 1) * 64;

    const int srow = wave * 16 + (lane >> 2);
    const int scol = (lane & 3) * 8;
    const bf16* gA0 = A + (size_t)(m0 + srow) * 1024 + scol;
    const bf16* gB0 = Bt + (size_t)(n0 + srow) * 1024 + scol;
    bf16* lA = &As[wave * 16 * 32];
    bf16* lB = &Bs[wave * 16 * 32];

    floatx4 acc[4][4] = {};

    for (int k0 = 0; k0 < 1024; k0 += 32) {
        gload16(gA0 + k0, lA);
        gload16(gA0 + 64 * 1024 + k0, lA + 64 * 32);
        gload16(gB0 + k0, lB);
        gload16(gB0 + 64 * 1024 + k0, lB + 64 * 32);
        __syncthreads();
        bf16x8 af[4], bf_[4];
#pragma unroll
        for (int i = 0; i < 4; i++)
            af[i] = *(bf16x8*)&As[(wm + i * 16 + l16) * 32 + quad * 8];
#pragma unroll
        for (int j = 0; j < 4; j++)
            bf_[j] = *(bf16x8*)&Bs[(wn + j * 16 + l16) * 32 + quad * 8];
#pragma unroll
        for (int i = 0; i < 4; i++)
#pragma unroll
            for (int j = 0; j < 4; j++)
                acc[i][j] = MFMA16(af[i], bf_[j], acc[i][j]);
        __syncthreads();
    }

#pragma unroll
    for (int i = 0; i < 4; i++)
#pragma unroll
        for (int j = 0; j < 4; j++) {
            const int col = n0 + wn + j * 16 + l16;
            const float bvv = bias[col];
#pragma unroll
            for (int r = 0; r < 4; r++) {
                const int gm = m0 + wm + i * 16 + quad * 4 + r;
                outC[(size_t)gm * 1024 + col] = acc[i][j][r] + bvv;
            }
        }
}

// ---------------------------------------------------------------------------
extern "C" void kernel_launch(void* const* d_in, const int* in_sizes, int n_in,
                              void* d_out, int out_size, void* d_ws, size_t ws_size,
                              hipStream_t stream) {
    const float* x  = (const float*)d_in[0];
    const float* wq = (const float*)d_in[1];
    const float* bq = (const float*)d_in[2];
    const float* wk = (const float*)d_in[3];
    const float* bk = (const float*)d_in[4];
    const float* wv = (const float*)d_in[5];
    const float* bv = (const float*)d_in[6];
    const float* wo = (const float*)d_in[7];
    const float* bo = (const float*)d_in[8];
    const float* alpha = (const float*)d_in[9];

    char* ws = (char*)d_ws;
    const size_t MB = 1024 * 1024;
    bf16* wqkv_h = (bf16*)(ws);              // 6 MB
    bf16* wqkv_l = (bf16*)(ws + 6 * MB);     // 6 MB
    bf16* wo_h   = (bf16*)(ws + 12 * MB);    // 2 MB
    float* knG   = (float*)(ws + 14 * MB);   // 0.25 MB
    bf16* x_h    = (bf16*)(ws + 16 * MB);    // 8 MB
    bf16* x_l    = (bf16*)(ws + 24 * MB);    // 8 MB
    bf16* Q_h    = (bf16*)(ws + 32 * MB);    // 8 MB
    bf16* Q_l    = (bf16*)(ws + 40 * MB);    // 8 MB
    bf16* K_h    = (bf16*)(ws + 48 * MB);    // 8 MB
    bf16* K_l    = (bf16*)(ws + 56 * MB);    // 8 MB
    bf16* Vt_g   = (bf16*)(ws + 64 * MB);    // 8 MB, [B,H,D,S]
    bf16* Ob     = (bf16*)(ws);              // aliases wqkv (dead after QKV GEMM)

    prep_kernel<<<dim3(32, 32, 5), dim3(32, 8), 0, stream>>>(
        x, wq, wk, wv, wo, x_h, x_l, wqkv_h, wqkv_l, wo_h);
    gemm_qkv3<<<dim3(32, 24), 256, 0, stream>>>(
        x_h, x_l, wqkv_h, wqkv_l, bq, bk, bv, Q_h, Q_l, K_h, K_l, Vt_g);
    kn_kernel<<<dim3(256), 256, 0, stream>>>(K_h, K_l, knG);
    attn_kernel<<<dim3(32, 16), 256, 0, stream>>>(
        Q_h, Q_l, K_h, K_l, Vt_g, knG, Ob, alpha);
    gemm_out<<<dim3(32, 8), 256, 0, stream>>>(Ob, wo_h, bo, (float*)d_out);
}

// Round 10
// 280.471 us; speedup vs baseline: 1.0916x; 1.0916x over previous
//
#include <hip/hip_runtime.h>
#include <hip/hip_bf16.h>
#include <math.h>

typedef __bf16 bf16;
typedef bf16 bf16x4 __attribute__((ext_vector_type(4)));
typedef bf16 bf16x8 __attribute__((ext_vector_type(8)));
typedef float floatx4 __attribute__((ext_vector_type(4)));

#define MFMA16(a, b, c) __builtin_amdgcn_mfma_f32_16x16x32_bf16(a, b, c, 0, 0, 0)

__device__ __forceinline__ void split2(float v, bf16& h, bf16& l) {
    h = (bf16)v;
    l = (bf16)(v - (float)h);
}

// async global->LDS, 16 B per lane; LDS dest = wave-uniform base + lane*16
__device__ __forceinline__ void gload16(const bf16* g, bf16* l) {
    __builtin_amdgcn_global_load_lds(
        (const __attribute__((address_space(1))) void*)g,
        (__attribute__((address_space(3))) void*)l, 16, 0, 0);
}

// ---------------------------------------------------------------------------
// K0: z<4: transpose+split fp32 weights W[k][n] -> hi/lo bf16 Wt[n][k]
//     z==4: split x fp32 -> hi/lo bf16 (flat)
// ---------------------------------------------------------------------------
__global__ void prep_kernel(const float* __restrict__ xf,
                            const float* __restrict__ wq, const float* __restrict__ wk,
                            const float* __restrict__ wv, const float* __restrict__ wo,
                            bf16* __restrict__ xh, bf16* __restrict__ xl,
                            bf16* __restrict__ wt_qkv_h, bf16* __restrict__ wt_qkv_l,
                            bf16* __restrict__ wt_o_h) {
    const int z = blockIdx.z;
    if (z == 4) {
        const int tid = threadIdx.y * 32 + threadIdx.x;
        const int bid = blockIdx.y * 32 + blockIdx.x;
        const size_t i = ((size_t)bid * 256 + tid) * 16;
#pragma unroll
        for (int half = 0; half < 2; half++) {
            float4 a = *(const float4*)(xf + i + half * 8);
            float4 b = *(const float4*)(xf + i + half * 8 + 4);
            bf16x8 oh, ol;
            float f[8] = {a.x, a.y, a.z, a.w, b.x, b.y, b.z, b.w};
#pragma unroll
            for (int j = 0; j < 8; j++) { bf16 h, l; split2(f[j], h, l); oh[j] = h; ol[j] = l; }
            *(bf16x8*)(xh + i + half * 8) = oh;
            *(bf16x8*)(xl + i + half * 8) = ol;
        }
        return;
    }
    const float* src = (z == 0) ? wq : (z == 1) ? wk : (z == 2) ? wv : wo;
    bf16* dsth = (z < 3) ? (wt_qkv_h + (size_t)z * 1024 * 1024) : wt_o_h;
    bf16* dstl = (z < 3) ? (wt_qkv_l + (size_t)z * 1024 * 1024) : nullptr;
    __shared__ float tile[32][33];
    const int x0 = blockIdx.x * 32, y0 = blockIdx.y * 32;
    const int tx = threadIdx.x, ty = threadIdx.y;  // (32,8)
    for (int i = 0; i < 32; i += 8)
        tile[ty + i][tx] = src[(size_t)(y0 + ty + i) * 1024 + x0 + tx];
    __syncthreads();
    for (int i = 0; i < 32; i += 8) {
        bf16 h, l;
        split2(tile[tx][ty + i], h, l);
        dsth[(size_t)(x0 + ty + i) * 1024 + y0 + tx] = h;
        if (dstl) dstl[(size_t)(x0 + ty + i) * 1024 + y0 + tx] = l;
    }
}

// ---------------------------------------------------------------------------
// K1a: Q+K GEMM (N=2048), 3-term split-bf16, m97 staging.
// Writes hi/lo pairs [B,H,S,D].
// ---------------------------------------------------------------------------
__global__ __launch_bounds__(256, 2) void gemm_qk3(
    const bf16* __restrict__ Ah, const bf16* __restrict__ Al,
    const bf16* __restrict__ Bth, const bf16* __restrict__ Btl,
    const float* __restrict__ bq, const float* __restrict__ bk,
    bf16* __restrict__ Qh, bf16* __restrict__ Ql,
    bf16* __restrict__ Kh, bf16* __restrict__ Kl) {
    __shared__ bf16 Ash[128 * 32];
    __shared__ bf16 Asl[128 * 32];
    __shared__ bf16 Bsh[128 * 32];
    __shared__ bf16 Bsl[128 * 32];

    const int t = threadIdx.x;
    const int lane = t & 63, wave = t >> 6;
    const int quad = lane >> 4, l16 = lane & 15;
    const int m0 = blockIdx.x * 128, n0 = blockIdx.y * 128;
    const int wm = (wave >> 1) * 64, wn = (wave & 1) * 64;

    const int srow = wave * 16 + (lane >> 2);
    const int scol = (lane & 3) * 8;
    const bf16* gAh = Ah + (size_t)(m0 + srow) * 1024 + scol;
    const bf16* gAl = Al + (size_t)(m0 + srow) * 1024 + scol;
    const bf16* gBh = Bth + (size_t)(n0 + srow) * 1024 + scol;
    const bf16* gBl = Btl + (size_t)(n0 + srow) * 1024 + scol;
    bf16* lAh = &Ash[wave * 16 * 32];
    bf16* lAl = &Asl[wave * 16 * 32];
    bf16* lBh = &Bsh[wave * 16 * 32];
    bf16* lBl = &Bsl[wave * 16 * 32];

    floatx4 acc[4][4] = {};

    for (int k0 = 0; k0 < 1024; k0 += 32) {
        gload16(gAh + k0, lAh);
        gload16(gAh + 64 * 1024 + k0, lAh + 64 * 32);
        gload16(gBh + k0, lBh);
        gload16(gBh + 64 * 1024 + k0, lBh + 64 * 32);
        gload16(gAl + k0, lAl);
        gload16(gAl + 64 * 1024 + k0, lAl + 64 * 32);
        gload16(gBl + k0, lBl);
        gload16(gBl + 64 * 1024 + k0, lBl + 64 * 32);
        __syncthreads();
        bf16x8 afh[4], bfh[4], afl[4], bfl[4];
#pragma unroll
        for (int i = 0; i < 4; i++) {
            afh[i] = *(bf16x8*)&Ash[(wm + i * 16 + l16) * 32 + quad * 8];
            afl[i] = *(bf16x8*)&Asl[(wm + i * 16 + l16) * 32 + quad * 8];
        }
#pragma unroll
        for (int j = 0; j < 4; j++) {
            bfh[j] = *(bf16x8*)&Bsh[(wn + j * 16 + l16) * 32 + quad * 8];
            bfl[j] = *(bf16x8*)&Bsl[(wn + j * 16 + l16) * 32 + quad * 8];
        }
#pragma unroll
        for (int i = 0; i < 4; i++)
#pragma unroll
            for (int j = 0; j < 4; j++) {
                acc[i][j] = MFMA16(afh[i], bfh[j], acc[i][j]);
                acc[i][j] = MFMA16(afh[i], bfl[j], acc[i][j]);
                acc[i][j] = MFMA16(afl[i], bfh[j], acc[i][j]);
            }
        __syncthreads();
    }

    const int which = n0 >> 10;  // 0=Q 1=K
    const float* bias = (which == 0) ? bq : bk;
    bf16* Dh = (which == 0) ? Qh : Kh;
    bf16* Dl = (which == 0) ? Ql : Kl;
#pragma unroll
    for (int i = 0; i < 4; i++)
#pragma unroll
        for (int j = 0; j < 4; j++) {
            const int col = n0 + wn + j * 16 + l16;
            const int o = col & 1023;
            const int h = o >> 6, d = o & 63;
            const float bvv = bias[o];
            const int gm0 = m0 + wm + i * 16 + quad * 4;
            const int b = gm0 >> 11;
#pragma unroll
            for (int r = 0; r < 4; r++) {
                const int gm = gm0 + r;
                const int s = gm & 2047;
                const size_t idx = (size_t)((b * 16 + h) * 2048 + s) * 64 + d;
                const float val = acc[i][j][r] + bvv;
                bf16 hi, lo;
                split2(val, hi, lo);
                Dh[idx] = hi;
                Dl[idx] = lo;
            }
        }
}

// ---------------------------------------------------------------------------
// K1b: V GEMM (N=1024), 1-term bf16, m97 staging, 16 KB LDS.
// Stores TRANSPOSED Vt[B,H,D,S].
// ---------------------------------------------------------------------------
__global__ __launch_bounds__(256, 2) void gemm_v(
    const bf16* __restrict__ Ah, const bf16* __restrict__ Bth,
    const float* __restrict__ bv, bf16* __restrict__ VtG) {
    __shared__ bf16 As[128 * 32];
    __shared__ bf16 Bs[128 * 32];

    const int t = threadIdx.x;
    const int lane = t & 63, wave = t >> 6;
    const int quad = lane >> 4, l16 = lane & 15;
    const int m0 = blockIdx.x * 128, n0 = blockIdx.y * 128;  // n0 within V slab
    const int wm = (wave >> 1) * 64, wn = (wave & 1) * 64;

    const int srow = wave * 16 + (lane >> 2);
    const int scol = (lane & 3) * 8;
    const bf16* gA0 = Ah + (size_t)(m0 + srow) * 1024 + scol;
    const bf16* gB0 = Bth + (size_t)(2048 + n0 + srow) * 1024 + scol;  // V slab of wqkv
    bf16* lA = &As[wave * 16 * 32];
    bf16* lB = &Bs[wave * 16 * 32];

    floatx4 acc[4][4] = {};

    for (int k0 = 0; k0 < 1024; k0 += 32) {
        gload16(gA0 + k0, lA);
        gload16(gA0 + 64 * 1024 + k0, lA + 64 * 32);
        gload16(gB0 + k0, lB);
        gload16(gB0 + 64 * 1024 + k0, lB + 64 * 32);
        __syncthreads();
        bf16x8 af[4], bf_[4];
#pragma unroll
        for (int i = 0; i < 4; i++)
            af[i] = *(bf16x8*)&As[(wm + i * 16 + l16) * 32 + quad * 8];
#pragma unroll
        for (int j = 0; j < 4; j++)
            bf_[j] = *(bf16x8*)&Bs[(wn + j * 16 + l16) * 32 + quad * 8];
#pragma unroll
        for (int i = 0; i < 4; i++)
#pragma unroll
            for (int j = 0; j < 4; j++)
                acc[i][j] = MFMA16(af[i], bf_[j], acc[i][j]);
        __syncthreads();
    }

#pragma unroll
    for (int i = 0; i < 4; i++)
#pragma unroll
        for (int j = 0; j < 4; j++) {
            const int o = (n0 + wn + j * 16 + l16) & 1023;
            const int h = o >> 6, d = o & 63;
            const float bvv = bv[o];
            const int gm0 = m0 + wm + i * 16 + quad * 4;
            const int b = gm0 >> 11;
            bf16x4 pv;
#pragma unroll
            for (int r = 0; r < 4; r++) pv[r] = (bf16)(acc[i][j][r] + bvv);
            const int s0 = gm0 & 2047;
            *(bf16x4*)&VtG[((size_t)((b * 16 + h) * 64 + d)) * 2048 + s0] = pv;
        }
}

// ---------------------------------------------------------------------------
// K1c: precompute ||k||^2 per key row (fp32 from hi+lo), knG[bh*2048+s]
// ---------------------------------------------------------------------------
__global__ void kn_kernel(const bf16* __restrict__ Kh, const bf16* __restrict__ Kl,
                          float* __restrict__ knG) {
    const int i = blockIdx.x * 256 + threadIdx.x;
    const bf16* ph = Kh + (size_t)i * 64;
    const bf16* pl = Kl + (size_t)i * 64;
    float s = 0.f;
#pragma unroll
    for (int d0 = 0; d0 < 64; d0 += 8) {
        bf16x8 vh = *(const bf16x8*)(ph + d0);
        bf16x8 vl = *(const bf16x8*)(pl + d0);
#pragma unroll
        for (int j = 0; j < 8; j++) { float x = (float)vh[j] + (float)vl[j]; s += x * x; }
    }
    knG[i] = s;
}

// ---------------------------------------------------------------------------
// K2: flash attention, YAT scores, transposed orientation, 32 q per wave,
//   double-buffered staging, CONSTANT-SHIFT softmax (no online max):
//   scores >= 0; exp2-domain shift 110 keeps p in [2^-110, 2^90] — exact
//   softmax up to fp range, no per-chunk max tracking or rescaling.
// ---------------------------------------------------------------------------
__global__ __launch_bounds__(256, 2) void attn_kernel(
    const bf16* __restrict__ Qh, const bf16* __restrict__ Ql,
    const bf16* __restrict__ Kh, const bf16* __restrict__ Kl,
    const bf16* __restrict__ VtG, const float* __restrict__ knG,
    bf16* __restrict__ O, const float* __restrict__ alphap) {
    __shared__ bf16 Ksh[2][64 * 72];
    __shared__ bf16 Ksl[2][64 * 72];
    __shared__ bf16 Vs[2][64 * 72];
    __shared__ bf16 Pt[4][32 * 72];
    __shared__ float knL[2][64];

    const int t = threadIdx.x, lane = t & 63, wave = t >> 6;
    const int quad = lane >> 4, l16 = lane & 15;
    const int bh = blockIdx.x;
    const int qw = blockIdx.y * 128 + wave * 32;

    const float alpha = alphap[0];
    const float C = powf(8.0f / log1pf(64.0f), alpha) * 1.44269504f;

    const size_t qrow0 = ((size_t)bh * 2048 + qw + l16) * 64;
    const size_t qrow1 = qrow0 + 16 * 64;
    bf16x8 bq0h[2], bq1h[2], bq0l[2], bq1l[2];
    bq0h[0] = *(const bf16x8*)(Qh + qrow0 + quad * 8);
    bq1h[0] = *(const bf16x8*)(Qh + qrow0 + 32 + quad * 8);
    bq0l[0] = *(const bf16x8*)(Ql + qrow0 + quad * 8);
    bq1l[0] = *(const bf16x8*)(Ql + qrow0 + 32 + quad * 8);
    bq0h[1] = *(const bf16x8*)(Qh + qrow1 + quad * 8);
    bq1h[1] = *(const bf16x8*)(Qh + qrow1 + 32 + quad * 8);
    bq0l[1] = *(const bf16x8*)(Ql + qrow1 + quad * 8);
    bq1l[1] = *(const bf16x8*)(Ql + qrow1 + 32 + quad * 8);

    float qne[2];
#pragma unroll
    for (int qg = 0; qg < 2; qg++) {
        float qn = 0.f;
#pragma unroll
        for (int j = 0; j < 8; j++) {
            float x0 = (float)bq0h[qg][j] + (float)bq0l[qg][j];
            float x1 = (float)bq1h[qg][j] + (float)bq1l[qg][j];
            qn += x0 * x0 + x1 * x1;
        }
        qn += __shfl_xor(qn, 16, 64);
        qn += __shfl_xor(qn, 32, 64);
        qne[qg] = qn + 1e-5f;
    }

    floatx4 acco[2][4] = {};
    float l_i[2] = {0.f, 0.f};

    const int srow = t >> 3;
    const int scol = (t & 7) * 8;
    const size_t vrow0 = ((size_t)bh * 64 + srow) * 2048;
    const size_t vrow1 = ((size_t)bh * 64 + srow + 32) * 2048;
    const float* knB = knG + (size_t)bh * 2048;

    auto do_chunk = [&](int ib) {
        const bf16* KshC = Ksh[ib];
        const bf16* KslC = Ksl[ib];
        const bf16* VsC = Vs[ib];
        const float* knC = knL[ib];
        bf16* Pw = Pt[wave];
        float rs0 = 0.f, rs1 = 0.f;
#pragma unroll
        for (int sub = 0; sub < 4; sub++) {
            bf16x8 a0h = *(bf16x8*)&KshC[(sub * 16 + l16) * 72 + quad * 8];
            bf16x8 a1h = *(bf16x8*)&KshC[(sub * 16 + l16) * 72 + 32 + quad * 8];
            bf16x8 a0l = *(bf16x8*)&KslC[(sub * 16 + l16) * 72 + quad * 8];
            bf16x8 a1l = *(bf16x8*)&KslC[(sub * 16 + l16) * 72 + 32 + quad * 8];
            floatx4 ac0 = {}, ac1 = {};
            ac0 = MFMA16(a0h, bq0h[0], ac0);
            ac0 = MFMA16(a1h, bq1h[0], ac0);
            ac0 = MFMA16(a0h, bq0l[0], ac0);
            ac0 = MFMA16(a1h, bq1l[0], ac0);
            ac0 = MFMA16(a0l, bq0h[0], ac0);
            ac0 = MFMA16(a1l, bq1h[0], ac0);
            ac1 = MFMA16(a0h, bq0h[1], ac1);
            ac1 = MFMA16(a1h, bq1h[1], ac1);
            ac1 = MFMA16(a0h, bq0l[1], ac1);
            ac1 = MFMA16(a1h, bq1l[1], ac1);
            ac1 = MFMA16(a0l, bq0h[1], ac1);
            ac1 = MFMA16(a1l, bq1h[1], ac1);
            const floatx4 knv = *(const floatx4*)&knC[sub * 16 + quad * 4];
            bf16x4 pv0, pv1;
#pragma unroll
            for (int r = 0; r < 4; r++) {
                const float d0 = ac0[r];
                const float d1 = ac1[r];
                const float e0 = fmaf(-2.0f, d0, qne[0] + knv[r]);
                const float e1 = fmaf(-2.0f, d1, qne[1] + knv[r]);
                const float t0 = C * d0 * d0;
                const float t1 = C * d1 * d1;
                const float s0 = fmaf(t0, __builtin_amdgcn_rcpf(e0), -110.0f);
                const float s1 = fmaf(t1, __builtin_amdgcn_rcpf(e1), -110.0f);
                const float p0 = __builtin_amdgcn_exp2f(s0);
                const float p1 = __builtin_amdgcn_exp2f(s1);
                rs0 += p0;
                rs1 += p1;
                pv0[r] = (bf16)p0;
                pv1[r] = (bf16)p1;
            }
            *(bf16x4*)&Pw[l16 * 72 + sub * 16 + quad * 4] = pv0;
            *(bf16x4*)&Pw[(16 + l16) * 72 + sub * 16 + quad * 4] = pv1;
        }
        rs0 += __shfl_xor(rs0, 16, 64);
        rs0 += __shfl_xor(rs0, 32, 64);
        rs1 += __shfl_xor(rs1, 16, 64);
        rs1 += __shfl_xor(rs1, 32, 64);
        l_i[0] += rs0;
        l_i[1] += rs1;

        bf16x8 bp0[2], bp1[2];
#pragma unroll
        for (int qg = 0; qg < 2; qg++) {
            bp0[qg] = *(bf16x8*)&Pw[(qg * 16 + l16) * 72 + quad * 8];
            bp1[qg] = *(bf16x8*)&Pw[(qg * 16 + l16) * 72 + 32 + quad * 8];
        }
#pragma unroll
        for (int dsub = 0; dsub < 4; dsub++) {
            bf16x8 a0 = *(bf16x8*)&VsC[(dsub * 16 + l16) * 72 + quad * 8];
            bf16x8 a1 = *(bf16x8*)&VsC[(dsub * 16 + l16) * 72 + 32 + quad * 8];
            acco[0][dsub] = MFMA16(a0, bp0[0], acco[0][dsub]);
            acco[0][dsub] = MFMA16(a1, bp1[0], acco[0][dsub]);
            acco[1][dsub] = MFMA16(a0, bp0[1], acco[1][dsub]);
            acco[1][dsub] = MFMA16(a1, bp1[1], acco[1][dsub]);
        }
    };

    {
        const size_t kb = (size_t)(bh * 2048) * 64;
        bf16x8 k0 = *(const bf16x8*)(Kh + kb + srow * 64 + scol);
        bf16x8 k1 = *(const bf16x8*)(Kh + kb + (32 + srow) * 64 + scol);
        bf16x8 c0 = *(const bf16x8*)(Kl + kb + srow * 64 + scol);
        bf16x8 c1 = *(const bf16x8*)(Kl + kb + (32 + srow) * 64 + scol);
        bf16x8 v0 = *(const bf16x8*)(VtG + vrow0 + scol);
        bf16x8 v1 = *(const bf16x8*)(VtG + vrow1 + scol);
        *(bf16x8*)&Ksh[0][srow * 72 + scol] = k0;
        *(bf16x8*)&Ksh[0][(32 + srow) * 72 + scol] = k1;
        *(bf16x8*)&Ksl[0][srow * 72 + scol] = c0;
        *(bf16x8*)&Ksl[0][(32 + srow) * 72 + scol] = c1;
        *(bf16x8*)&Vs[0][srow * 72 + scol] = v0;
        *(bf16x8*)&Vs[0][(32 + srow) * 72 + scol] = v1;
        if (t < 16) *(float4*)&knL[0][t * 4] = *(const float4*)(knB + t * 4);
    }
    __syncthreads();

    for (int ic = 0; ic < 31; ic++) {
        const int cur = ic & 1, nxt = cur ^ 1;
        const int kc = (ic + 1) * 64;
        const size_t kb = (size_t)(bh * 2048 + kc) * 64;
        bf16x8 nk0 = *(const bf16x8*)(Kh + kb + srow * 64 + scol);
        bf16x8 nk1 = *(const bf16x8*)(Kh + kb + (32 + srow) * 64 + scol);
        bf16x8 nc0 = *(const bf16x8*)(Kl + kb + srow * 64 + scol);
        bf16x8 nc1 = *(const bf16x8*)(Kl + kb + (32 + srow) * 64 + scol);
        bf16x8 nv0 = *(const bf16x8*)(VtG + vrow0 + kc + scol);
        bf16x8 nv1 = *(const bf16x8*)(VtG + vrow1 + kc + scol);
        float4 nkn;
        if (t < 16) nkn = *(const float4*)(knB + kc + t * 4);

        do_chunk(cur);

        *(bf16x8*)&Ksh[nxt][srow * 72 + scol] = nk0;
        *(bf16x8*)&Ksh[nxt][(32 + srow) * 72 + scol] = nk1;
        *(bf16x8*)&Ksl[nxt][srow * 72 + scol] = nc0;
        *(bf16x8*)&Ksl[nxt][(32 + srow) * 72 + scol] = nc1;
        *(bf16x8*)&Vs[nxt][srow * 72 + scol] = nv0;
        *(bf16x8*)&Vs[nxt][(32 + srow) * 72 + scol] = nv1;
        if (t < 16) *(float4*)&knL[nxt][t * 4] = nkn;
        __syncthreads();
    }
    do_chunk(1);

    const int b = bh >> 4, h = bh & 15;
#pragma unroll
    for (int qg = 0; qg < 2; qg++) {
        const int s = qw + qg * 16 + l16;
        const float rl = 1.0f / l_i[qg];
        const size_t obase = (size_t)(b * 2048 + s) * 1024 + h * 64;
#pragma unroll
        for (int dsub = 0; dsub < 4; dsub++) {
            bf16x4 ov;
#pragma unroll
            for (int r = 0; r < 4; r++) ov[r] = (bf16)(acco[qg][dsub][r] * rl);
            *(bf16x4*)&O[obase + dsub * 16 + quad * 4] = ov;
        }
    }
}

// ---------------------------------------------------------------------------
// K3: out-proj GEMM (single bf16 pass, m97 staging), fp32 output
// ---------------------------------------------------------------------------
__global__ __launch_bounds__(256, 2) void gemm_out(
    const bf16* __restrict__ A, const bf16* __restrict__ Bt,
    const float* __restrict__ bias, float* __restrict__ outC) {
    __shared__ bf16 As[128 * 32];
    __shared__ bf16 Bs[128 * 32];

    const int t = threadIdx.x;
    const int lane = t & 63, wave = t >> 6;
    const int quad = lane >> 4, l16 = lane & 15;
    const int m0 = blockIdx.x * 128, n0 = blockIdx.y * 128;
    const int wm = (wave >> 1) * 64, wn = (wave & 1) * 64;

    const int srow = wave * 16 + (lane >> 2);
    const int scol = (lane & 3) * 8;
    const bf16* gA0 = A + (size_t)(m0 + srow) * 1024 + scol;
    const bf16* gB0 = Bt + (size_t)(n0 + srow) * 1024 + scol;
    bf16* lA = &As[wave * 16 * 32];
    bf16* lB = &Bs[wave * 16 * 32];

    floatx4 acc[4][4] = {};

    for (int k0 = 0; k0 < 1024; k0 += 32) {
        gload16(gA0 + k0, lA);
        gload16(gA0 + 64 * 1024 + k0, lA + 64 * 32);
        gload16(gB0 + k0, lB);
        gload16(gB0 + 64 * 1024 + k0, lB + 64 * 32);
        __syncthreads();
        bf16x8 af[4], bf_[4];
#pragma unroll
        for (int i = 0; i < 4; i++)
            af[i] = *(bf16x8*)&As[(wm + i * 16 + l16) * 32 + quad * 8];
#pragma unroll
        for (int j = 0; j < 4; j++)
            bf_[j] = *(bf16x8*)&Bs[(wn + j * 16 + l16) * 32 + quad * 8];
#pragma unroll
        for (int i = 0; i < 4; i++)
#pragma unroll
            for (int j = 0; j < 4; j++)
                acc[i][j] = MFMA16(af[i], bf_[j], acc[i][j]);
        __syncthreads();
    }

#pragma unroll
    for (int i = 0; i < 4; i++)
#pragma unroll
        for (int j = 0; j < 4; j++) {
            const int col = n0 + wn + j * 16 + l16;
            const float bvv = bias[col];
#pragma unroll
            for (int r = 0; r < 4; r++) {
                const int gm = m0 + wm + i * 16 + quad * 4 + r;
                outC[(size_t)gm * 1024 + col] = acc[i][j][r] + bvv;
            }
        }
}

// ---------------------------------------------------------------------------
extern "C" void kernel_launch(void* const* d_in, const int* in_sizes, int n_in,
                              void* d_out, int out_size, void* d_ws, size_t ws_size,
                              hipStream_t stream) {
    const float* x  = (const float*)d_in[0];
    const float* wq = (const float*)d_in[1];
    const float* bq = (const float*)d_in[2];
    const float* wk = (const float*)d_in[3];
    const float* bk = (const float*)d_in[4];
    const float* wv = (const float*)d_in[5];
    const float* bv = (const float*)d_in[6];
    const float* wo = (const float*)d_in[7];
    const float* bo = (const float*)d_in[8];
    const float* alpha = (const float*)d_in[9];

    char* ws = (char*)d_ws;
    const size_t MB = 1024 * 1024;
    bf16* wqkv_h = (bf16*)(ws);              // 6 MB
    bf16* wqkv_l = (bf16*)(ws + 6 * MB);     // 6 MB
    bf16* wo_h   = (bf16*)(ws + 12 * MB);    // 2 MB
    float* knG   = (float*)(ws + 14 * MB);   // 0.25 MB
    bf16* x_h    = (bf16*)(ws + 16 * MB);    // 8 MB
    bf16* x_l    = (bf16*)(ws + 24 * MB);    // 8 MB
    bf16* Q_h    = (bf16*)(ws + 32 * MB);    // 8 MB
    bf16* Q_l    = (bf16*)(ws + 40 * MB);    // 8 MB
    bf16* K_h    = (bf16*)(ws + 48 * MB);    // 8 MB
    bf16* K_l    = (bf16*)(ws + 56 * MB);    // 8 MB
    bf16* Vt_g   = (bf16*)(ws + 64 * MB);    // 8 MB, [B,H,D,S]
    bf16* Ob     = (bf16*)(ws);              // aliases wqkv (dead after QKV GEMMs)

    prep_kernel<<<dim3(32, 32, 5), dim3(32, 8), 0, stream>>>(
        x, wq, wk, wv, wo, x_h, x_l, wqkv_h, wqkv_l, wo_h);
    gemm_qk3<<<dim3(32, 16), 256, 0, stream>>>(
        x_h, x_l, wqkv_h, wqkv_l, bq, bk, Q_h, Q_l, K_h, K_l);
    gemm_v<<<dim3(32, 8), 256, 0, stream>>>(x_h, wqkv_h, bv, Vt_g);
    kn_kernel<<<dim3(256), 256, 0, stream>>>(K_h, K_l, knG);
    attn_kernel<<<dim3(32, 16), 256, 0, stream>>>(
        Q_h, Q_l, K_h, K_l, Vt_g, knG, Ob, alpha);
    gemm_out<<<dim3(32, 8), 256, 0, stream>>>(Ob, wo_h, bo, (float*)d_out);
}